// Round 23
// baseline (79.058 us; speedup 1.0000x reference)
//
#include <hip/hip_runtime.h>

#define N     384
#define BSZ   192
#define NM1   383
#define D     1024
#define DELTA 0.1f
#define NT    24                    // 16-row panels / tiles per dim
#define NTILES (NT * (NT + 1) / 2)  // 300 upper-tri tiles
#define PANEL 16384                 // halfs per panel: 16 rows * 1024
#define SPIN_TICKS 5000ULL          // 50.70 us (calibrated R10)

typedef __attribute__((ext_vector_type(8))) short bf16x8;
typedef __attribute__((ext_vector_type(4))) float f32x4;

__device__ __forceinline__ void tail_spin() {
    unsigned long long t0 = __builtin_amdgcn_s_memrealtime();
    while (__builtin_amdgcn_s_memrealtime() - t0 < SPIN_TICKS)
        __builtin_amdgcn_s_sleep(2);
}

__device__ __forceinline__ const float* feat_row(const float* feats, int i) {
    // features laid out [192][2][1024]; logical row i of the [384,1024] concat
    int b = (i < BSZ) ? i : (i - BSZ);
    int s = (i < BSZ) ? 0 : 1;
    return feats + (size_t)(b * 2 + s) * D;
}

__device__ __forceinline__ unsigned short f2bf(float x) {  // RNE f32->bf16
    unsigned u = __builtin_bit_cast(unsigned, x);
    u = (u + 0x7FFFu + ((u >> 16) & 1u)) >> 16;
    return (unsigned short)u;
}
__device__ __forceinline__ float bf2f(unsigned short h) {
    unsigned u = ((unsigned)h) << 16;
    return __builtin_bit_cast(float, u);
}

// Fragment-major tiled index: (row, k) -> [row/16][k/8][row%16][k%8]
__device__ __forceinline__ size_t tidx(int row, int k) {
    return (size_t)(row >> 4) * PANEL + (size_t)(k >> 3) * 128
         + (size_t)(row & 15) * 8 + (k & 7);
}

// cvt (R22 form): 768 blocks x 128 thr, 3 blocks/CU exact.
__global__ __launch_bounds__(128) void k_cvt(const float* __restrict__ feats,
                                             unsigned short* __restrict__ Ht,
                                             unsigned short* __restrict__ Lt,
                                             float* __restrict__ sqh) {
    const int b = blockIdx.x, tid = threadIdx.x;
    const int i = b >> 1, hh = b & 1;
    __shared__ float redp[2];

    const float4 v = ((const float4*)feat_row(feats, i))[hh * 128 + tid];
    float p = 0.f;
    p = fmaf(v.x, v.x, p); p = fmaf(v.y, v.y, p);
    p = fmaf(v.z, v.z, p); p = fmaf(v.w, v.w, p);
    ushort4 h, l;
    h.x = f2bf(v.x); l.x = f2bf(v.x - bf2f(h.x));
    h.y = f2bf(v.y); l.y = f2bf(v.y - bf2f(h.y));
    h.z = f2bf(v.z); l.z = f2bf(v.z - bf2f(h.z));
    h.w = f2bf(v.w); l.w = f2bf(v.w - bf2f(h.w));
    const size_t o = tidx(i, 4 * (hh * 128 + tid));   // 8B-aligned slot
    *(ushort4*)(Ht + o) = h;
    *(ushort4*)(Lt + o) = l;

#pragma unroll
    for (int off = 32; off; off >>= 1) p += __shfl_xor(p, off);
    if ((tid & 63) == 0) redp[tid >> 6] = p;
    __syncthreads();
    if (tid == 0) sqh[b] = redp[0] + redp[1];
}

// Gram via MFMA on fragment-major H/L (unchanged; ~2.9us in R11).
__global__ __launch_bounds__(256) void k_gram(const unsigned short* __restrict__ Ht,
                                              const unsigned short* __restrict__ Lt,
                                              const float* __restrict__ sqh,
                                              float* __restrict__ z) {
    int t = blockIdx.x, bi = 0;
    while (t >= NT - bi) { t -= NT - bi; ++bi; }
    const int bj = bi + t;
    const bool diag = (bi == bj);

    const int tid = threadIdx.x;
    const int lane = tid & 63, wv = tid >> 6;

    const size_t aBase = (size_t)bi * PANEL + (size_t)(wv * 32 + (lane >> 4)) * 128
                       + (size_t)(lane & 15) * 8;
    const size_t bBase = (size_t)bj * PANEL + (size_t)(wv * 32 + (lane >> 4)) * 128
                       + (size_t)(lane & 15) * 8;

    f32x4 aHH = {0.f,0.f,0.f,0.f}, aHL = {0.f,0.f,0.f,0.f}, aLH = {0.f,0.f,0.f,0.f};
#pragma unroll
    for (int s = 0; s < 8; ++s) {
        bf16x8 aH = *(const bf16x8*)(Ht + aBase + s * 512);
        bf16x8 aL = *(const bf16x8*)(Lt + aBase + s * 512);
        bf16x8 bH = *(const bf16x8*)(Ht + bBase + s * 512);
        bf16x8 bL = *(const bf16x8*)(Lt + bBase + s * 512);
        aHH = __builtin_amdgcn_mfma_f32_16x16x32_bf16(aH, bH, aHH, 0, 0, 0);
        aHL = __builtin_amdgcn_mfma_f32_16x16x32_bf16(aH, bL, aHL, 0, 0, 0);
        aLH = __builtin_amdgcn_mfma_f32_16x16x32_bf16(aL, bH, aLH, 0, 0, 0);
    }
    __shared__ f32x4 red[4][64];
    red[wv][lane] = aHH + aHL + aLH;
    __syncthreads();
    const int ls = tid & 63, r = tid >> 6;
    float g = red[0][ls][r] + red[1][ls][r] + red[2][ls][r] + red[3][ls][r];
    // C/D layout (verified): col = lane&15, row = (lane>>4)*4 + reg
    const int jj = bj * 16 + (ls & 15);
    const int ii = bi * 16 + ((ls >> 4) << 2) + r;
    if (ii != jj && (!diag || ii < jj)) {
        const float sqi = sqh[2 * ii] + sqh[2 * ii + 1];
        const float sqj = sqh[2 * jj] + sqh[2 * jj + 1];
        float sd = fmaxf(sqi + sqj - 2.f * g, 0.f);
        float v  = sqrtf(sd);
        z[ii * NM1 + (jj < ii ? jj : jj - 1)] = v;
        z[jj * NM1 + (ii < jj ? ii : ii - 1)] = v;
    }
}

// 768 blocks x 512 thr, 3/CU (R21). NEW: symmetric triangular sweep
// (j<k only, x2; pair function symmetric, diagonal zero) — slot-static
// structure, boundary slot lane-predicated. Correction also halved (k>anchor,
// x2). + PROBE: 50.7us tail spin -> k_main lands in top-5; real = dur-50.7.
__global__ __launch_bounds__(512) void k_main(const float* __restrict__ z,
                                              const int* __restrict__ labels,
                                              float* __restrict__ partial) {
    const int b = blockIdx.x, tid = threadIdx.x;
    const int i = b >> 1, h = b & 1;
    const int lane = tid & 63, wv = tid >> 6;
    __shared__ int cnt[64], startv[64], cur[64];
    __shared__ float rankd[64];
    __shared__ float2 zr[N];      // sorted (z, rank*DELTA); slot 383 = (0,0)
    __shared__ unsigned grs[N];   // lo | hi<<9 per sorted slot

    if (tid < 64) cnt[tid] = 0;
    float zi = 0.f;
    int   ya = 0;
    const int li = labels[(i < BSZ) ? i : (i - BSZ)];
    if (tid < NM1) {
        zi = z[i * NM1 + tid];
        int col = tid + (tid >= i ? 1 : 0);
        ya = abs(li - labels[(col < BSZ) ? col : (col - BSZ)]);
    }
    __syncthreads();
    if (tid < NM1) atomicAdd(&cnt[ya], 1);
    __syncthreads();
    if (tid < 64) {                    // wave-0 parallel exclusive scans
        const int c  = cnt[tid];
        const int nz = (c > 0) ? 1 : 0;
        int sc = c, sn = nz;
#pragma unroll
        for (int d = 1; d < 64; d <<= 1) {
            int tc = __shfl_up(sc, d);
            int tn = __shfl_up(sn, d);
            if (tid >= d) { sc += tc; sn += tn; }
        }
        startv[tid] = sc - c;
        cur[tid]    = sc - c;
        rankd[tid]  = (float)(sn - nz) * DELTA;
    }
    if (tid == 511) { zr[NM1] = make_float2(0.f, 0.f); grs[NM1] = 0u; }
    __syncthreads();
    if (tid < NM1) {
        int pos = atomicAdd(&cur[ya], 1);
        zr[pos]  = make_float2(zi, rankd[ya]);
        grs[pos] = (unsigned)startv[ya] | ((unsigned)(startv[ya] + cnt[ya]) << 9);
    }
    __syncthreads();

    // 6 k-slots per lane (k = lane + 64*s; slot-5/lane-63 = pad)
    float2 S[6];
#pragma unroll
    for (int s = 0; s < 6; ++s) S[s] = zr[lane + 64 * s];

    // triangular sweep: wave w covers j in [12w,12w+12) u [372-12w,384-12w)
    // (uniform ~84 j-slot iters/wave); only k > j kept.
    const int w    = h * 8 + wv;
    const int r1lo = 12 * w;
    const int r2lo = 372 - 12 * w;

    float acc0 = 0.f, acc1 = 0.f, acc2 = 0.f, acc3 = 0.f;
#define GRP_FULL(J, E) do {                                                   \
        const float4 qa = *(const float4*)&zr[(J)];                           \
        const float4 qb = *(const float4*)&zr[(J) + 2];                       \
        float t_;                                                             \
        t_ = fabsf((E).x - qa.x) - fabsf((E).y - qa.y); acc0 = fmaf(t_, t_, acc0); \
        t_ = fabsf((E).x - qa.z) - fabsf((E).y - qa.w); acc1 = fmaf(t_, t_, acc1); \
        t_ = fabsf((E).x - qb.x) - fabsf((E).y - qb.y); acc2 = fmaf(t_, t_, acc2); \
        t_ = fabsf((E).x - qb.z) - fabsf((E).y - qb.w); acc3 = fmaf(t_, t_, acc3); \
    } while (0)
#define GRP_PRED(J, E, JL) do {                                               \
        const float4 qa = *(const float4*)&zr[(J)];                           \
        const float4 qb = *(const float4*)&zr[(J) + 2];                       \
        float t_, c_;                                                         \
        t_ = fabsf((E).x - qa.x) - fabsf((E).y - qa.y); c_ = t_ * t_;         \
        acc0 += (lane > (JL) + 0) ? c_ : 0.f;                                 \
        t_ = fabsf((E).x - qa.z) - fabsf((E).y - qa.w); c_ = t_ * t_;         \
        acc1 += (lane > (JL) + 1) ? c_ : 0.f;                                 \
        t_ = fabsf((E).x - qb.x) - fabsf((E).y - qb.y); c_ = t_ * t_;         \
        acc2 += (lane > (JL) + 2) ? c_ : 0.f;                                 \
        t_ = fabsf((E).x - qb.z) - fabsf((E).y - qb.w); c_ = t_ * t_;         \
        acc3 += (lane > (JL) + 3) ? c_ : 0.f;                                 \
    } while (0)
#pragma unroll
    for (int s = 0; s < 6; ++s) {
        const float2 e  = S[s];
        const int lo64  = s << 6;
        const int hi64  = lo64 + 64;
        // range 1: [r1lo, r1lo+12)
        {
            const int fhi = (r1lo + 12 < lo64) ? r1lo + 12 : lo64;
            for (int j = r1lo; j < fhi; j += 4) GRP_FULL(j, e);
            const int plo = (r1lo > lo64) ? r1lo : lo64;
            const int phi = (r1lo + 12 < hi64) ? r1lo + 12 : hi64;
            for (int j = plo; j < phi; j += 4) GRP_PRED(j, e, j - lo64);
        }
        // range 2: [r2lo, r2lo+12)
        {
            const int fhi = (r2lo + 12 < lo64) ? r2lo + 12 : lo64;
            for (int j = r2lo; j < fhi; j += 4) GRP_FULL(j, e);
            const int plo = (r2lo > lo64) ? r2lo : lo64;
            const int phi = (r2lo + 12 < hi64) ? r2lo + 12 : hi64;
            for (int j = plo; j < phi; j += 4) GRP_PRED(j, e, j - lo64);
        }
    }
#undef GRP_FULL
#undef GRP_PRED
    float sum = 2.f * (((acc0 + acc1) + (acc2 + acc3)));

    // pad compensation: each real j paired once with pad-k in the triangle;
    // after x2 that is 2*P extra -> h==1 block subtracts 2*(z-r)^2 per slot.
    if (h == 1 && tid < NM1) {
        float2 e2 = zr[tid];
        float d = e2.x - e2.y;
        sum = fmaf(-2.f * d, d, sum);
    }

    // correction over same-y pairs, halved (k > anchor, x2; diagonal = 0)
    {
        const int anchor = h * 192 + tid;
        if (tid < 192 && anchor < NM1) {
            const float    zj = zr[anchor].x;
            const unsigned g  = grs[anchor];
            const int hi = (g >> 9) & 0x1FF;
            float cs = 0.f;
            for (int k = anchor + 1; k < hi; ++k) {
                float a = fabsf(zr[k].x - zj);
                cs += a * __builtin_amdgcn_rcpf(1.f + __expf(DELTA - a)) - a * a;
            }
            sum += 2.f * cs;
        }
    }

#pragma unroll
    for (int off = 32; off; off >>= 1) sum += __shfl_xor(sum, off);
    __shared__ float part[8];
    if (lane == 0) part[wv] = sum;
    __syncthreads();
    if (tid == 0) {
        float ps = 0.f;
#pragma unroll
        for (int w2 = 0; w2 < 8; ++w2) ps += part[w2];
        partial[b] = ps;
    }
    tail_spin();   // PROBE: k_main real = top5 dur - 50.7us
}

__global__ __launch_bounds__(512) void k_fin(const float* __restrict__ partial,
                                             float* __restrict__ out) {
    const int tid = threadIdx.x;
    double s = 0.0;
    for (int t = tid; t < 2 * N; t += 512) s += (double)partial[t];
#pragma unroll
    for (int off = 32; off; off >>= 1) s += __shfl_xor(s, off);
    __shared__ double dp[8];
    if ((tid & 63) == 0) dp[tid >> 6] = s;
    __syncthreads();
    if (tid == 0) {
        double ds = 0.0;
#pragma unroll
        for (int w = 0; w < 8; ++w) ds += dp[w];
        const double M = (double)N * (double)NM1 * (double)NM1;
        out[0] = (float)(ds / M);
    }
}

extern "C" void kernel_launch(void* const* d_in, const int* in_sizes, int n_in,
                              void* d_out, int out_size, void* d_ws, size_t ws_size,
                              hipStream_t stream) {
    const float* feats  = (const float*)d_in[0];
    const int*   labels = (const int*)d_in[1];
    float*       out    = (float*)d_out;

    // ws layout (~2.2 MB total):
    char* ws = (char*)d_ws;
    float*          sqh     = (float*)ws;                          // 3072 B
    float*          partial = (float*)(ws + 4096);                 // 3072 B
    unsigned short* Ht      = (unsigned short*)(ws + 16384);       // 768 KiB
    unsigned short* Lt      = (unsigned short*)(ws + 16384 + 786432);        // 768 KiB
    float*          z       = (float*)(ws + 16384 + 2 * 786432);   // 588 KiB

    k_cvt <<<2 * N, 128, 0, stream>>>(feats, Ht, Lt, sqh);
    k_gram<<<NTILES, 256, 0, stream>>>(Ht, Lt, sqh, z);
    k_main<<<2 * N, 512, 0, stream>>>(z, labels, partial);
    k_fin <<<1, 512, 0, stream>>>(partial, out);
}

// Round 24
// 26.082 us; speedup vs baseline: 3.0311x; 3.0311x over previous
//
#include <hip/hip_runtime.h>

#define N     384
#define BSZ   192
#define NM1   383
#define D     1024
#define DELTA 0.1f
#define NT    24                    // 16-row panels / tiles per dim
#define NTILES (NT * (NT + 1) / 2)  // 300 upper-tri tiles
#define PANEL 16384                 // halfs per panel: 16 rows * 1024

typedef __attribute__((ext_vector_type(8))) short bf16x8;
typedef __attribute__((ext_vector_type(4))) float f32x4;

__device__ __forceinline__ const float* feat_row(const float* feats, int i) {
    // features laid out [192][2][1024]; logical row i of the [384,1024] concat
    int b = (i < BSZ) ? i : (i - BSZ);
    int s = (i < BSZ) ? 0 : 1;
    return feats + (size_t)(b * 2 + s) * D;
}

__device__ __forceinline__ unsigned short f2bf(float x) {  // RNE f32->bf16
    unsigned u = __builtin_bit_cast(unsigned, x);
    u = (u + 0x7FFFu + ((u >> 16) & 1u)) >> 16;
    return (unsigned short)u;
}
__device__ __forceinline__ float bf2f(unsigned short h) {
    unsigned u = ((unsigned)h) << 16;
    return __builtin_bit_cast(float, u);
}

// Fragment-major tiled index: (row, k) -> [row/16][k/8][row%16][k%8]
__device__ __forceinline__ size_t tidx(int row, int k) {
    return (size_t)(row >> 4) * PANEL + (size_t)(k >> 3) * 128
         + (size_t)(row & 15) * 8 + (k & 7);
}

// cvt, 768 blocks x 128 thr = 3 blocks/CU exact. Block (i, hh) = row i,
// k-half hh. Per-half |f|^2 partial -> sqh[b]; k_gram sums the halves.
__global__ __launch_bounds__(128) void k_cvt(const float* __restrict__ feats,
                                             unsigned short* __restrict__ Ht,
                                             unsigned short* __restrict__ Lt,
                                             float* __restrict__ sqh) {
    const int b = blockIdx.x, tid = threadIdx.x;
    const int i = b >> 1, hh = b & 1;
    __shared__ float redp[2];

    const float4 v = ((const float4*)feat_row(feats, i))[hh * 128 + tid];
    float p = 0.f;
    p = fmaf(v.x, v.x, p); p = fmaf(v.y, v.y, p);
    p = fmaf(v.z, v.z, p); p = fmaf(v.w, v.w, p);
    ushort4 h, l;
    h.x = f2bf(v.x); l.x = f2bf(v.x - bf2f(h.x));
    h.y = f2bf(v.y); l.y = f2bf(v.y - bf2f(h.y));
    h.z = f2bf(v.z); l.z = f2bf(v.z - bf2f(h.z));
    h.w = f2bf(v.w); l.w = f2bf(v.w - bf2f(h.w));
    const size_t o = tidx(i, 4 * (hh * 128 + tid));   // 8B-aligned slot
    *(ushort4*)(Ht + o) = h;
    *(ushort4*)(Lt + o) = l;

#pragma unroll
    for (int off = 32; off; off >>= 1) p += __shfl_xor(p, off);
    if ((tid & 63) == 0) redp[tid >> 6] = p;
    __syncthreads();
    if (tid == 0) sqh[b] = redp[0] + redp[1];
}

// Gram via MFMA on fragment-major H/L (~2.9us measured in R11).
__global__ __launch_bounds__(256) void k_gram(const unsigned short* __restrict__ Ht,
                                              const unsigned short* __restrict__ Lt,
                                              const float* __restrict__ sqh,
                                              float* __restrict__ z) {
    int t = blockIdx.x, bi = 0;
    while (t >= NT - bi) { t -= NT - bi; ++bi; }
    const int bj = bi + t;
    const bool diag = (bi == bj);

    const int tid = threadIdx.x;
    const int lane = tid & 63, wv = tid >> 6;

    const size_t aBase = (size_t)bi * PANEL + (size_t)(wv * 32 + (lane >> 4)) * 128
                       + (size_t)(lane & 15) * 8;
    const size_t bBase = (size_t)bj * PANEL + (size_t)(wv * 32 + (lane >> 4)) * 128
                       + (size_t)(lane & 15) * 8;

    f32x4 aHH = {0.f,0.f,0.f,0.f}, aHL = {0.f,0.f,0.f,0.f}, aLH = {0.f,0.f,0.f,0.f};
#pragma unroll
    for (int s = 0; s < 8; ++s) {
        bf16x8 aH = *(const bf16x8*)(Ht + aBase + s * 512);
        bf16x8 aL = *(const bf16x8*)(Lt + aBase + s * 512);
        bf16x8 bH = *(const bf16x8*)(Ht + bBase + s * 512);
        bf16x8 bL = *(const bf16x8*)(Lt + bBase + s * 512);
        aHH = __builtin_amdgcn_mfma_f32_16x16x32_bf16(aH, bH, aHH, 0, 0, 0);
        aHL = __builtin_amdgcn_mfma_f32_16x16x32_bf16(aH, bL, aHL, 0, 0, 0);
        aLH = __builtin_amdgcn_mfma_f32_16x16x32_bf16(aL, bH, aLH, 0, 0, 0);
    }
    __shared__ f32x4 red[4][64];
    red[wv][lane] = aHH + aHL + aLH;
    __syncthreads();
    const int ls = tid & 63, r = tid >> 6;
    float g = red[0][ls][r] + red[1][ls][r] + red[2][ls][r] + red[3][ls][r];
    // C/D layout (verified): col = lane&15, row = (lane>>4)*4 + reg
    const int jj = bj * 16 + (ls & 15);
    const int ii = bi * 16 + ((ls >> 4) << 2) + r;
    if (ii != jj && (!diag || ii < jj)) {
        const float sqi = sqh[2 * ii] + sqh[2 * ii + 1];
        const float sqj = sqh[2 * jj] + sqh[2 * jj + 1];
        float sd = fmaxf(sqi + sqj - 2.f * g, 0.f);
        float v  = sqrtf(sd);
        z[ii * NM1 + (jj < ii ? jj : jj - 1)] = v;
        z[jj * NM1 + (ii < jj ? ii : ii - 1)] = v;
    }
}

// 768 blocks x 512 thr = 3 blocks/CU (R21 balance win). Register-resident
// sort inputs, wave-0 shfl scan, LDS-atomic scatter; sweep: wave = 24-j
// subrange, lane = 6 reg k-slots, static full unroll (measured-best form;
// R23's triangular variant was SLOWER -- dynamic-bound loop overhead).
__global__ __launch_bounds__(512) void k_main(const float* __restrict__ z,
                                              const int* __restrict__ labels,
                                              float* __restrict__ partial) {
    const int b = blockIdx.x, tid = threadIdx.x;
    const int i = b >> 1, h = b & 1;
    const int lane = tid & 63, wv = tid >> 6;
    __shared__ int cnt[64], startv[64], cur[64];
    __shared__ float rankd[64];
    __shared__ float2 zr[N];      // sorted (z, rank*DELTA); slot 383 = (0,0)
    __shared__ unsigned grs[N];   // lo | hi<<9 per sorted slot

    if (tid < 64) cnt[tid] = 0;
    float zi = 0.f;
    int   ya = 0;
    const int li = labels[(i < BSZ) ? i : (i - BSZ)];
    if (tid < NM1) {
        zi = z[i * NM1 + tid];
        int col = tid + (tid >= i ? 1 : 0);
        ya = abs(li - labels[(col < BSZ) ? col : (col - BSZ)]);
    }
    __syncthreads();
    if (tid < NM1) atomicAdd(&cnt[ya], 1);
    __syncthreads();
    if (tid < 64) {                    // wave-0 parallel exclusive scans
        const int c  = cnt[tid];
        const int nz = (c > 0) ? 1 : 0;
        int sc = c, sn = nz;
#pragma unroll
        for (int d = 1; d < 64; d <<= 1) {
            int tc = __shfl_up(sc, d);
            int tn = __shfl_up(sn, d);
            if (tid >= d) { sc += tc; sn += tn; }
        }
        startv[tid] = sc - c;
        cur[tid]    = sc - c;
        rankd[tid]  = (float)(sn - nz) * DELTA;
    }
    if (tid == 511) { zr[NM1] = make_float2(0.f, 0.f); grs[NM1] = 0u; }
    __syncthreads();
    if (tid < NM1) {
        int pos = atomicAdd(&cur[ya], 1);
        zr[pos]  = make_float2(zi, rankd[ya]);
        grs[pos] = (unsigned)startv[ya] | ((unsigned)(startv[ya] + cnt[ya]) << 9);
    }
    __syncthreads();

    // 6 k-slots per lane: each wave covers all 384 slots (incl pad-k)
    float2 S[6];
#pragma unroll
    for (int s = 0; s < 6; ++s) S[s] = zr[lane + 64 * s];

    // 24 j per wave (subrange h*8+wv of 16); 3 batches of 8 j, 4 b128 reads
    const int j0 = (h * 8 + wv) * 24;
    float a0[6] = {0,0,0,0,0,0}, a1[6] = {0,0,0,0,0,0};
#pragma unroll
    for (int bb = 0; bb < 3; ++bb) {
        const int j = j0 + bb * 8;
        const float4 qA = *(const float4*)&zr[j];       // j even: 16B aligned
        const float4 qB = *(const float4*)&zr[j + 2];
        const float4 qC = *(const float4*)&zr[j + 4];
        const float4 qD = *(const float4*)&zr[j + 6];
#pragma unroll
        for (int s = 0; s < 6; ++s) {
            float t;
            t = fabsf(S[s].x - qA.x) - fabsf(S[s].y - qA.y); a0[s] = fmaf(t, t, a0[s]);
            t = fabsf(S[s].x - qA.z) - fabsf(S[s].y - qA.w); a1[s] = fmaf(t, t, a1[s]);
            t = fabsf(S[s].x - qB.x) - fabsf(S[s].y - qB.y); a0[s] = fmaf(t, t, a0[s]);
            t = fabsf(S[s].x - qB.z) - fabsf(S[s].y - qB.w); a1[s] = fmaf(t, t, a1[s]);
            t = fabsf(S[s].x - qC.x) - fabsf(S[s].y - qC.y); a0[s] = fmaf(t, t, a0[s]);
            t = fabsf(S[s].x - qC.z) - fabsf(S[s].y - qC.w); a1[s] = fmaf(t, t, a1[s]);
            t = fabsf(S[s].x - qD.x) - fabsf(S[s].y - qD.y); a0[s] = fmaf(t, t, a0[s]);
            t = fabsf(S[s].x - qD.z) - fabsf(S[s].y - qD.w); a1[s] = fmaf(t, t, a1[s]);
        }
    }
    float sum = 0.f;
#pragma unroll
    for (int s = 0; s < 6; ++s) sum += a0[s] + a1[s];

    // pad compensation, split per half:
    //  block h sweeps pad-k x J_h -> subtract sum_{j in J_h, j real} (zj-rj)^2
    //  block h=1 also sweeps pad-j x all k -> subtract sum_{k real} (zk-rk)^2
    {
        float comp = 0.f;
        if (h == 0) {
            if (tid < 192) { float2 e = zr[tid];       float d = e.x - e.y; comp += d * d; }
        } else {
            if (tid < 191) { float2 e = zr[192 + tid]; float d = e.x - e.y; comp += d * d; }
            if (tid < NM1) { float2 e = zr[tid];       float d = e.x - e.y; comp += d * d; }
        }
        sum -= comp;
    }

    // correction over same-y pairs, anchors split per half: h*192 + [0,192)
    {
        const int anchor = h * 192 + tid;
        if (tid < 192 && anchor < NM1) {
            const float    zj = zr[anchor].x;
            const unsigned g  = grs[anchor];
            const int lo = g & 0x1FF;
            const int hi = (g >> 9) & 0x1FF;
            float cs = 0.f;
            for (int k = lo; k < hi; ++k) {
                float a = fabsf(zr[k].x - zj);
                cs += a * __builtin_amdgcn_rcpf(1.f + __expf(DELTA - a)) - a * a;
            }
            sum += cs;
        }
    }

#pragma unroll
    for (int off = 32; off; off >>= 1) sum += __shfl_xor(sum, off);
    __shared__ float part[8];
    if (lane == 0) part[wv] = sum;
    __syncthreads();
    if (tid == 0) {
        float ps = 0.f;
#pragma unroll
        for (int w = 0; w < 8; ++w) ps += part[w];
        partial[b] = ps;
    }
}

__global__ __launch_bounds__(512) void k_fin(const float* __restrict__ partial,
                                             float* __restrict__ out) {
    const int tid = threadIdx.x;
    double s = 0.0;
    for (int t = tid; t < 2 * N; t += 512) s += (double)partial[t];
#pragma unroll
    for (int off = 32; off; off >>= 1) s += __shfl_xor(s, off);
    __shared__ double dp[8];
    if ((tid & 63) == 0) dp[tid >> 6] = s;
    __syncthreads();
    if (tid == 0) {
        double ds = 0.0;
#pragma unroll
        for (int w = 0; w < 8; ++w) ds += dp[w];
        const double M = (double)N * (double)NM1 * (double)NM1;
        out[0] = (float)(ds / M);
    }
}

extern "C" void kernel_launch(void* const* d_in, const int* in_sizes, int n_in,
                              void* d_out, int out_size, void* d_ws, size_t ws_size,
                              hipStream_t stream) {
    const float* feats  = (const float*)d_in[0];
    const int*   labels = (const int*)d_in[1];
    float*       out    = (float*)d_out;

    // ws layout (~2.2 MB total):
    char* ws = (char*)d_ws;
    float*          sqh     = (float*)ws;                          // 3072 B
    float*          partial = (float*)(ws + 4096);                 // 3072 B
    unsigned short* Ht      = (unsigned short*)(ws + 16384);       // 768 KiB
    unsigned short* Lt      = (unsigned short*)(ws + 16384 + 786432);        // 768 KiB
    float*          z       = (float*)(ws + 16384 + 2 * 786432);   // 588 KiB

    k_cvt <<<2 * N, 128, 0, stream>>>(feats, Ht, Lt, sqh);
    k_gram<<<NTILES, 256, 0, stream>>>(Ht, Lt, sqh, z);
    k_main<<<2 * N, 512, 0, stream>>>(z, labels, partial);
    k_fin <<<1, 512, 0, stream>>>(partial, out);
}